// Round 1
// baseline (480.758 us; speedup 1.0000x reference)
//
#include <hip/hip_runtime.h>
#include <math.h>
#include <stdint.h>

#define NUM_CL 21
#define NB 4
#define H 512
#define W 512
#define PH 171
#define PW 171
#define NHH 169
#define NWW 169
#define M_TOT (NHH*NWW)          // 28561
#define NCP (NB*NUM_CL)          // 84
#define PPLANE (PH*PW)           // 29241
#define POOL_ELEMS (NCP*PPLANE)  // 2456244
#define ACC_PER 189
#define SLICES 16
#define MCHUNK ((M_TOT + SLICES - 1)/SLICES)   // 1786
#define POS_ALPHA 5e-4

// enumeration index for symmetric upper-tri pairs as produced in kernelB
__device__ __forceinline__ int upIdx(int lo, int hi) {
    return lo*9 - (lo*(lo-1))/2 + (hi - lo);
}
__device__ __forceinline__ int tri(int d, int e) { return d*(d+1)/2 + e; }

// ---------------- Kernel A: fused sigmoid + BCE + 3x3/3 max-pool ----------------
__global__ __launch_bounds__(256) void kernelA(
    const float* __restrict__ logits, const int* __restrict__ labels,
    float* __restrict__ pooledP, unsigned char* __restrict__ pooledL,
    double* __restrict__ bce_sum, unsigned long long* __restrict__ valid_cnt)
{
    int idx = blockIdx.x * 256 + threadIdx.x;
    float bce_acc = 0.f;
    unsigned int cnt = 0;
    if (idx < POOL_ELEMS) {
        int pw = idx % PW;
        int t  = idx / PW;
        int ph = t % PH;  t /= PH;
        int c  = t % NUM_CL;
        int n  = t / NUM_CL;
        int r0 = 3*ph - 1, c0 = 3*pw - 1;
        int r1 = (r0 + 3 < H) ? r0 + 3 : H;
        int c1 = (c0 + 3 < W) ? c0 + 3 : W;
        if (r0 < 0) r0 = 0;
        if (c0 < 0) c0 = 0;
        const float* lg = logits + (size_t)(n*NUM_CL + c) * (size_t)(H*W);
        const int*   lb = labels + (size_t)n * (size_t)(H*W);
        float pmax = -INFINITY;
        float lmax = 0.f;
        for (int r = r0; r < r1; ++r) {
            for (int q = c0; q < c1; ++q) {
                float x  = lg[r*W + q];
                int lab  = lb[r*W + q];
                int m    = (lab < NUM_CL) ? 1 : 0;
                float wm = (float)m;
                float y  = (m && lab == c) ? 1.f : 0.f;
                float ax = fabsf(x);
                float te = expf(-ax);
                float sp = log1pf(te);
                bce_acc += wm * (fmaxf(x, 0.f) - x*y + sp);
                float sig = (x >= 0.f) ? (1.f/(1.f + te)) : (te/(1.f + te));
                float p = sig * wm + 1e-6f;
                pmax = fmaxf(pmax, p);
                lmax = fmaxf(lmax, y);
                if (c == 0) cnt += (unsigned)m;
            }
        }
        pooledP[idx] = pmax;
        pooledL[idx] = (unsigned char)(lmax > 0.5f);
    }
    __shared__ float sb[256];
    __shared__ unsigned int sc[256];
    sb[threadIdx.x] = bce_acc;
    sc[threadIdx.x] = cnt;
    __syncthreads();
    #pragma unroll
    for (int s = 128; s > 0; s >>= 1) {
        if ((int)threadIdx.x < s) {
            sb[threadIdx.x] += sb[threadIdx.x + s];
            sc[threadIdx.x] += sc[threadIdx.x + s];
        }
        __syncthreads();
    }
    if (threadIdx.x == 0) {
        atomicAdd(bce_sum, (double)sb[0]);
        atomicAdd(valid_cnt, (unsigned long long)sc[0]);
    }
}

// ---------------- Kernel B: raw-moment accumulation for 9x9 covariances ----------------
__global__ __launch_bounds__(256) void kernelB(
    const float* __restrict__ pooledP, const unsigned char* __restrict__ pooledL,
    double* __restrict__ cov_acc)
{
    int nc    = blockIdx.x;
    int slice = blockIdx.y;
    const float* P = pooledP + (size_t)nc * PPLANE;
    const unsigned char* L = pooledL + (size_t)nc * PPLANE;

    float sl[9], sp[9], cll[45], cpp[45], clp[81];
    #pragma unroll
    for (int d = 0; d < 9; ++d) { sl[d] = 0.f; sp[d] = 0.f; }
    #pragma unroll
    for (int k = 0; k < 45; ++k) { cll[k] = 0.f; cpp[k] = 0.f; }
    #pragma unroll
    for (int k = 0; k < 81; ++k) clp[k] = 0.f;

    int mlo = slice * MCHUNK;
    int mhi = mlo + MCHUNK; if (mhi > M_TOT) mhi = M_TOT;
    for (int m = mlo + (int)threadIdx.x; m < mhi; m += 256) {
        int i = m / NWW;
        int j = m - i * NWW;
        int base = i * PW + j;
        float la[9], pr[9];
        #pragma unroll
        for (int dy = 0; dy < 3; ++dy) {
            #pragma unroll
            for (int dx = 0; dx < 3; ++dx) {
                int o = base + dy*PW + dx;
                pr[dy*3+dx] = P[o];
                la[dy*3+dx] = (float)L[o];
            }
        }
        #pragma unroll
        for (int d = 0; d < 9; ++d) { sl[d] += la[d]; sp[d] += pr[d]; }
        int k = 0;
        #pragma unroll
        for (int d = 0; d < 9; ++d) {
            #pragma unroll
            for (int e = d; e < 9; ++e) {
                cll[k] += la[d]*la[e];
                cpp[k] += pr[d]*pr[e];
                ++k;
            }
        }
        #pragma unroll
        for (int d = 0; d < 9; ++d) {
            #pragma unroll
            for (int e = 0; e < 9; ++e) clp[d*9+e] += la[d]*pr[e];
        }
    }

    __shared__ float red[4][ACC_PER];
    int lane = threadIdx.x & 63;
    int wave = threadIdx.x >> 6;

    auto wred = [&](float v) -> float {
        #pragma unroll
        for (int o = 32; o > 0; o >>= 1) v += __shfl_down(v, o, 64);
        return v;
    };

    #pragma unroll
    for (int d = 0; d < 9; ++d) { float r = wred(sl[d]); if (lane == 0) red[wave][d] = r; }
    #pragma unroll
    for (int d = 0; d < 9; ++d) { float r = wred(sp[d]); if (lane == 0) red[wave][9+d] = r; }
    #pragma unroll
    for (int k = 0; k < 45; ++k) { float r = wred(cll[k]); if (lane == 0) red[wave][18+k] = r; }
    #pragma unroll
    for (int k = 0; k < 45; ++k) { float r = wred(cpp[k]); if (lane == 0) red[wave][63+k] = r; }
    #pragma unroll
    for (int k = 0; k < 81; ++k) { float r = wred(clp[k]); if (lane == 0) red[wave][108+k] = r; }
    __syncthreads();

    for (int v = threadIdx.x; v < ACC_PER; v += 256) {
        float s = red[0][v] + red[1][v] + red[2][v] + red[3][v];
        atomicAdd(&cov_acc[(size_t)nc * ACC_PER + v], (double)s);
    }
}

// ---------------- Kernel C: per-(n,c) 9x9 solve + Cholesky logdet + final combine ----------------
__global__ __launch_bounds__(128) void kernelC(
    const double* __restrict__ cov_acc,
    const double* __restrict__ bce_sum,
    const unsigned long long* __restrict__ valid_cnt,
    float* __restrict__ out)
{
    int t = threadIdx.x;
    float contrib = 0.f;
    if (t < NCP) {
        const double* acc = cov_acc + (size_t)t * ACC_PER;
        const double Minv = 1.0 / (double)M_TOT;
        double Sl[9], Sp[9];
        #pragma unroll
        for (int d = 0; d < 9; ++d) { Sl[d] = acc[d]; Sp[d] = acc[9+d]; }

        float A[45];  // pr_cov + alpha*I (lower tri)
        float G[45];  // la_cov (lower tri), later appro_var
        float B[81];  // la_pr_cov rows, later W rows
        #pragma unroll
        for (int d = 0; d < 9; ++d) {
            #pragma unroll
            for (int e = 0; e <= d; ++e) {
                int ku = upIdx(e, d);
                double vp = acc[63+ku] - Sp[d]*Sp[e]*Minv;
                double vl = acc[18+ku] - Sl[d]*Sl[e]*Minv;
                if (d == e) vp += POS_ALPHA;
                A[tri(d,e)] = (float)vp;
                G[tri(d,e)] = (float)vl;
            }
        }
        #pragma unroll
        for (int d = 0; d < 9; ++d) {
            #pragma unroll
            for (int e = 0; e < 9; ++e)
                B[d*9+e] = (float)(acc[108 + d*9 + e] - Sl[d]*Sp[e]*Minv);
        }

        // Cholesky of A (lower, in place): A = L L^T
        #pragma unroll
        for (int d = 0; d < 9; ++d) {
            float s = A[tri(d,d)];
            #pragma unroll
            for (int f = 0; f < d; ++f) { float v = A[tri(d,f)]; s -= v*v; }
            float ldd = sqrtf(s);
            A[tri(d,d)] = ldd;
            float inv = 1.f / ldd;
            #pragma unroll
            for (int e = d+1; e < 9; ++e) {
                float s2 = A[tri(e,d)];
                #pragma unroll
                for (int f = 0; f < d; ++f) s2 -= A[tri(e,f)] * A[tri(d,f)];
                A[tri(e,d)] = s2 * inv;
            }
        }

        // forward substitution: row d of B <- solve L w = LP[d,:]^T
        #pragma unroll
        for (int d = 0; d < 9; ++d) {
            #pragma unroll
            for (int e = 0; e < 9; ++e) {
                float s = B[d*9+e];
                #pragma unroll
                for (int f = 0; f < e; ++f) s -= A[tri(e,f)] * B[d*9+f];
                B[d*9+e] = s / A[tri(e,e)];
            }
        }

        // appro_var = la_cov - W^T W + alpha*I  (lower tri, into G)
        #pragma unroll
        for (int d = 0; d < 9; ++d) {
            #pragma unroll
            for (int g = 0; g <= d; ++g) {
                float q = 0.f;
                #pragma unroll
                for (int e = 0; e < 9; ++e) q += B[d*9+e] * B[g*9+e];
                float v = G[tri(d,g)] - q;
                if (d == g) v += (float)POS_ALPHA;
                G[tri(d,g)] = v;
            }
        }

        // Cholesky of G, sum log(diag + 1e-8)
        float sumlog = 0.f;
        #pragma unroll
        for (int d = 0; d < 9; ++d) {
            float s = G[tri(d,d)];
            #pragma unroll
            for (int f = 0; f < d; ++f) { float v = G[tri(d,f)]; s -= v*v; }
            float ldd = sqrtf(s);
            G[tri(d,d)] = ldd;
            sumlog += logf(ldd + 1e-8f);
            float inv = 1.f / ldd;
            #pragma unroll
            for (int e = d+1; e < 9; ++e) {
                float s2 = G[tri(e,d)];
                #pragma unroll
                for (int f = 0; f < d; ++f) s2 -= G[tri(e,f)] * G[tri(d,f)];
                G[tri(e,d)] = s2 * inv;
            }
        }
        contrib = sumlog * (1.0f / 36.0f);   // /(N * HALF_D) = /(4*9)
    }

    __shared__ float sred[128];
    sred[t] = contrib;
    __syncthreads();
    #pragma unroll
    for (int s = 64; s > 0; s >>= 1) {
        if (t < s) sred[t] += sred[t + s];
        __syncthreads();
    }
    if (t == 0) {
        double bce_loss = bce_sum[0] / ((double)valid_cnt[0] + 1.0);
        out[0] = (float)(0.5 * bce_loss + 0.5 * (double)sred[0]);
    }
}

extern "C" void kernel_launch(void* const* d_in, const int* in_sizes, int n_in,
                              void* d_out, int out_size, void* d_ws, size_t ws_size,
                              hipStream_t stream)
{
    (void)in_sizes; (void)n_in; (void)out_size; (void)ws_size;
    const float* logits = (const float*)d_in[0];
    const int*   labels = (const int*)d_in[1];
    float* out = (float*)d_out;

    uint8_t* w = (uint8_t*)d_ws;
    double* bce_sum = (double*)w;                                  // 8 B
    unsigned long long* valid = (unsigned long long*)(w + 8);      // 8 B
    double* cov_acc = (double*)(w + 16);                           // 84*189*8 = 127008 B
    size_t acc_bytes = 16 + (size_t)NCP * ACC_PER * 8;             // 127024
    float* pooledP = (float*)(w + acc_bytes);                      // 9.8 MB
    unsigned char* pooledL = (unsigned char*)(w + acc_bytes + (size_t)POOL_ELEMS * 4); // 2.5 MB

    hipMemsetAsync(d_ws, 0, acc_bytes, stream);

    int blocksA = (POOL_ELEMS + 255) / 256;
    kernelA<<<blocksA, 256, 0, stream>>>(logits, labels, pooledP, pooledL, bce_sum, valid);
    kernelB<<<dim3(NCP, SLICES), 256, 0, stream>>>(pooledP, pooledL, cov_acc);
    kernelC<<<1, 128, 0, stream>>>(cov_acc, bce_sum, valid, out);
}

// Round 2
// 290.369 us; speedup vs baseline: 1.6557x; 1.6557x over previous
//
#include <hip/hip_runtime.h>
#include <math.h>
#include <stdint.h>

#define NUM_CL 21
#define NB 4
#define H 512
#define W 512
#define PH 171
#define PW 171
#define NHH 169
#define NWW 169
#define M_TOT (NHH*NWW)          // 28561
#define NCP (NB*NUM_CL)          // 84
#define PPLANE (PH*PW)           // 29241
#define POOL_ELEMS (NCP*PPLANE)  // 2456244
#define ACC_PER 189
#define SLICES 8
#define MCHUNK ((M_TOT + SLICES - 1)/SLICES)   // 3571
#define POS_ALPHA 5e-4

__device__ __forceinline__ int upIdx(int lo, int hi) {
    return lo*9 - (lo*(lo-1))/2 + (hi - lo);
}
__device__ __forceinline__ int tri(int d, int e) { return d*(d+1)/2 + e; }

// ---------------- Kernel A: fused sigmoid + BCE + 3x3/3 max-pool ----------------
// One block per (n, pooled-row ph). Labels loaded once to LDS; loop over 21
// classes with float4-coalesced logits loads; probs staged in LDS; 171 threads
// compute the pooled max per class.
__global__ __launch_bounds__(256) void kernelA(
    const float* __restrict__ logits, const int* __restrict__ labels,
    float* __restrict__ pooledP, unsigned char* __restrict__ pooledL,
    double* __restrict__ bce_sum, unsigned long long* __restrict__ valid_cnt)
{
    int blk = blockIdx.x;           // 0 .. NB*PH-1
    int ph  = blk % PH;
    int n   = blk / PH;
    int r0 = 3*ph - 1; if (r0 < 0) r0 = 0;
    int r1 = 3*ph + 2; if (r1 > H) r1 = H;
    int nr = r1 - r0;               // 2 (ph==0) or 3
    int nelem = nr * W;             // 1024 or 1536
    int n4 = nelem >> 2;

    __shared__ int   slab[3*W];
    __shared__ float sprob[3*W];
    __shared__ float rb[256];
    __shared__ unsigned int rc[256];

    int tid = threadIdx.x;

    // ---- load labels (int4) + count valid ----
    const int* lb = labels + (size_t)n * (H*W) + (size_t)r0 * W;
    unsigned int cnt = 0;
    for (int q4 = tid; q4 < n4; q4 += 256) {
        int4 l4 = ((const int4*)lb)[q4];
        ((int4*)slab)[q4] = l4;
        cnt += (l4.x < NUM_CL) + (l4.y < NUM_CL) + (l4.z < NUM_CL) + (l4.w < NUM_CL);
    }
    __syncthreads();

    float bce = 0.f;
    for (int c = 0; c < NUM_CL; ++c) {
        const float4* lg4 = (const float4*)(logits + ((size_t)(n*NUM_CL + c) * H + r0) * W);
        for (int q4 = tid; q4 < n4; q4 += 256) {
            float4 x4 = lg4[q4];
            int base = q4 << 2;
            float xs[4] = {x4.x, x4.y, x4.z, x4.w};
            float ps[4];
            #pragma unroll
            for (int k = 0; k < 4; ++k) {
                int lab = slab[base + k];
                float x = xs[k];
                float m = (lab < NUM_CL) ? 1.f : 0.f;
                float y = (lab == c) ? 1.f : 0.f;
                float ax = fabsf(x);
                float te = __expf(-ax);
                float splus = log1pf(te);
                bce += m * (fmaxf(x, 0.f) - x*y + splus);
                float sig = (x >= 0.f) ? (1.f/(1.f + te)) : (te/(1.f + te));
                ps[k] = sig * m + 1e-6f;
            }
            ((float4*)sprob)[q4] = make_float4(ps[0], ps[1], ps[2], ps[3]);
        }
        __syncthreads();
        if (tid < PW) {
            int pw = tid;
            int c0 = 3*pw - 1; if (c0 < 0) c0 = 0;
            int c1 = 3*pw + 2; if (c1 > W) c1 = W;
            float pmax = -INFINITY;
            int lmax = 0;
            for (int rr = 0; rr < nr; ++rr) {
                int ro = rr * W;
                for (int q = c0; q < c1; ++q) {
                    pmax = fmaxf(pmax, sprob[ro + q]);
                    lmax |= (slab[ro + q] == c);
                }
            }
            size_t o = ((size_t)(n*NUM_CL + c) * PH + ph) * PW + pw;
            pooledP[o] = pmax;
            pooledL[o] = (unsigned char)lmax;
        }
        __syncthreads();
    }

    // ---- block reduce BCE + valid count ----
    rb[tid] = bce;
    rc[tid] = cnt;
    __syncthreads();
    #pragma unroll
    for (int s = 128; s > 0; s >>= 1) {
        if (tid < s) { rb[tid] += rb[tid + s]; rc[tid] += rc[tid + s]; }
        __syncthreads();
    }
    if (tid == 0) {
        atomicAdd(bce_sum, (double)rb[0]);
        atomicAdd(valid_cnt, (unsigned long long)rc[0]);
    }
}

// ---------------- Kernel B: raw-moment accumulation, split into 2 register groups ----
__global__ __launch_bounds__(256) void kernelB(
    const float* __restrict__ pooledP, const unsigned char* __restrict__ pooledL,
    double* __restrict__ cov_acc)
{
    int nc    = blockIdx.x;
    int slice = blockIdx.y;
    int grp   = blockIdx.z;
    const float* P = pooledP + (size_t)nc * PPLANE;
    const unsigned char* L = pooledL + (size_t)nc * PPLANE;

    int mlo = slice * MCHUNK;
    int mhi = mlo + MCHUNK; if (mhi > M_TOT) mhi = M_TOT;

    __shared__ float red[4][108];
    int lane = threadIdx.x & 63;
    int wave = threadIdx.x >> 6;

    auto wred = [&](float v) -> float {
        #pragma unroll
        for (int o = 32; o > 0; o >>= 1) v += __shfl_down(v, o, 64);
        return v;
    };

    double* acc = cov_acc + (size_t)nc * ACC_PER;

    if (grp == 0) {
        float sl[9], sp[9], cll[45], cpp[45];
        #pragma unroll
        for (int d = 0; d < 9; ++d) { sl[d] = 0.f; sp[d] = 0.f; }
        #pragma unroll
        for (int k = 0; k < 45; ++k) { cll[k] = 0.f; cpp[k] = 0.f; }

        for (int m = mlo + (int)threadIdx.x; m < mhi; m += 256) {
            int i = m / NWW;
            int j = m - i * NWW;
            int base = i * PW + j;
            float la[9], pr[9];
            #pragma unroll
            for (int dy = 0; dy < 3; ++dy)
                #pragma unroll
                for (int dx = 0; dx < 3; ++dx) {
                    int o = base + dy*PW + dx;
                    pr[dy*3+dx] = P[o];
                    la[dy*3+dx] = (float)L[o];
                }
            #pragma unroll
            for (int d = 0; d < 9; ++d) { sl[d] += la[d]; sp[d] += pr[d]; }
            int k = 0;
            #pragma unroll
            for (int d = 0; d < 9; ++d)
                #pragma unroll
                for (int e = d; e < 9; ++e) {
                    cll[k] += la[d]*la[e];
                    cpp[k] += pr[d]*pr[e];
                    ++k;
                }
        }

        #pragma unroll
        for (int d = 0; d < 9; ++d) { float r = wred(sl[d]);  if (lane == 0) red[wave][d]     = r; }
        #pragma unroll
        for (int d = 0; d < 9; ++d) { float r = wred(sp[d]);  if (lane == 0) red[wave][9+d]   = r; }
        #pragma unroll
        for (int k = 0; k < 45; ++k) { float r = wred(cll[k]); if (lane == 0) red[wave][18+k] = r; }
        #pragma unroll
        for (int k = 0; k < 45; ++k) { float r = wred(cpp[k]); if (lane == 0) red[wave][63+k] = r; }
        __syncthreads();
        for (int v = threadIdx.x; v < 108; v += 256) {
            float s = red[0][v] + red[1][v] + red[2][v] + red[3][v];
            atomicAdd(&acc[v], (double)s);
        }
    } else {
        float clp[81];
        #pragma unroll
        for (int k = 0; k < 81; ++k) clp[k] = 0.f;

        for (int m = mlo + (int)threadIdx.x; m < mhi; m += 256) {
            int i = m / NWW;
            int j = m - i * NWW;
            int base = i * PW + j;
            float la[9], pr[9];
            #pragma unroll
            for (int dy = 0; dy < 3; ++dy)
                #pragma unroll
                for (int dx = 0; dx < 3; ++dx) {
                    int o = base + dy*PW + dx;
                    pr[dy*3+dx] = P[o];
                    la[dy*3+dx] = (float)L[o];
                }
            #pragma unroll
            for (int d = 0; d < 9; ++d)
                #pragma unroll
                for (int e = 0; e < 9; ++e) clp[d*9+e] += la[d]*pr[e];
        }

        #pragma unroll
        for (int k = 0; k < 81; ++k) { float r = wred(clp[k]); if (lane == 0) red[wave][k] = r; }
        __syncthreads();
        for (int v = threadIdx.x; v < 81; v += 256) {
            float s = red[0][v] + red[1][v] + red[2][v] + red[3][v];
            atomicAdd(&acc[108 + v], (double)s);
        }
    }
}

// ---------------- Kernel C: per-(n,c) 9x9 solve + Cholesky logdet + final combine ----------------
__global__ __launch_bounds__(128) void kernelC(
    const double* __restrict__ cov_acc,
    const double* __restrict__ bce_sum,
    const unsigned long long* __restrict__ valid_cnt,
    float* __restrict__ out)
{
    int t = threadIdx.x;
    float contrib = 0.f;
    if (t < NCP) {
        const double* acc = cov_acc + (size_t)t * ACC_PER;
        const double Minv = 1.0 / (double)M_TOT;
        double Sl[9], Sp[9];
        #pragma unroll
        for (int d = 0; d < 9; ++d) { Sl[d] = acc[d]; Sp[d] = acc[9+d]; }

        float A[45];  // pr_cov + alpha*I (lower tri)
        float G[45];  // la_cov (lower tri), later appro_var
        float B[81];  // la_pr_cov rows, later W rows
        #pragma unroll
        for (int d = 0; d < 9; ++d) {
            #pragma unroll
            for (int e = 0; e <= d; ++e) {
                int ku = upIdx(e, d);
                double vp = acc[63+ku] - Sp[d]*Sp[e]*Minv;
                double vl = acc[18+ku] - Sl[d]*Sl[e]*Minv;
                if (d == e) vp += POS_ALPHA;
                A[tri(d,e)] = (float)vp;
                G[tri(d,e)] = (float)vl;
            }
        }
        #pragma unroll
        for (int d = 0; d < 9; ++d) {
            #pragma unroll
            for (int e = 0; e < 9; ++e)
                B[d*9+e] = (float)(acc[108 + d*9 + e] - Sl[d]*Sp[e]*Minv);
        }

        // Cholesky of A (lower, in place)
        #pragma unroll
        for (int d = 0; d < 9; ++d) {
            float s = A[tri(d,d)];
            #pragma unroll
            for (int f = 0; f < d; ++f) { float v = A[tri(d,f)]; s -= v*v; }
            float ldd = sqrtf(s);
            A[tri(d,d)] = ldd;
            float inv = 1.f / ldd;
            #pragma unroll
            for (int e = d+1; e < 9; ++e) {
                float s2 = A[tri(e,d)];
                #pragma unroll
                for (int f = 0; f < d; ++f) s2 -= A[tri(e,f)] * A[tri(d,f)];
                A[tri(e,d)] = s2 * inv;
            }
        }

        // forward substitution: row d of B <- solve L w = LP[d,:]^T
        #pragma unroll
        for (int d = 0; d < 9; ++d) {
            #pragma unroll
            for (int e = 0; e < 9; ++e) {
                float s = B[d*9+e];
                #pragma unroll
                for (int f = 0; f < e; ++f) s -= A[tri(e,f)] * B[d*9+f];
                B[d*9+e] = s / A[tri(e,e)];
            }
        }

        // appro_var = la_cov - W W^T + alpha*I
        #pragma unroll
        for (int d = 0; d < 9; ++d) {
            #pragma unroll
            for (int g = 0; g <= d; ++g) {
                float q = 0.f;
                #pragma unroll
                for (int e = 0; e < 9; ++e) q += B[d*9+e] * B[g*9+e];
                float v = G[tri(d,g)] - q;
                if (d == g) v += (float)POS_ALPHA;
                G[tri(d,g)] = v;
            }
        }

        // Cholesky of G, sum log(diag + 1e-8)
        float sumlog = 0.f;
        #pragma unroll
        for (int d = 0; d < 9; ++d) {
            float s = G[tri(d,d)];
            #pragma unroll
            for (int f = 0; f < d; ++f) { float v = G[tri(d,f)]; s -= v*v; }
            float ldd = sqrtf(s);
            G[tri(d,d)] = ldd;
            sumlog += logf(ldd + 1e-8f);
            float inv = 1.f / ldd;
            #pragma unroll
            for (int e = d+1; e < 9; ++e) {
                float s2 = G[tri(e,d)];
                #pragma unroll
                for (int f = 0; f < d; ++f) s2 -= G[tri(e,f)] * G[tri(d,f)];
                G[tri(e,d)] = s2 * inv;
            }
        }
        contrib = sumlog * (1.0f / 36.0f);   // /(N * HALF_D) = /(4*9)
    }

    __shared__ float sred[128];
    sred[t] = contrib;
    __syncthreads();
    #pragma unroll
    for (int s = 64; s > 0; s >>= 1) {
        if (t < s) sred[t] += sred[t + s];
        __syncthreads();
    }
    if (t == 0) {
        double bce_loss = bce_sum[0] / ((double)valid_cnt[0] + 1.0);
        out[0] = (float)(0.5 * bce_loss + 0.5 * (double)sred[0]);
    }
}

extern "C" void kernel_launch(void* const* d_in, const int* in_sizes, int n_in,
                              void* d_out, int out_size, void* d_ws, size_t ws_size,
                              hipStream_t stream)
{
    (void)in_sizes; (void)n_in; (void)out_size; (void)ws_size;
    const float* logits = (const float*)d_in[0];
    const int*   labels = (const int*)d_in[1];
    float* out = (float*)d_out;

    uint8_t* w = (uint8_t*)d_ws;
    double* bce_sum = (double*)w;                                  // 8 B
    unsigned long long* valid = (unsigned long long*)(w + 8);      // 8 B
    double* cov_acc = (double*)(w + 16);                           // 84*189*8 = 127008 B
    size_t acc_bytes = 16 + (size_t)NCP * ACC_PER * 8;             // 127024
    float* pooledP = (float*)(w + acc_bytes);                      // 9.8 MB
    unsigned char* pooledL = (unsigned char*)(w + acc_bytes + (size_t)POOL_ELEMS * 4); // 2.5 MB

    hipMemsetAsync(d_ws, 0, acc_bytes, stream);

    kernelA<<<NB*PH, 256, 0, stream>>>(logits, labels, pooledP, pooledL, bce_sum, valid);
    kernelB<<<dim3(NCP, SLICES, 2), 256, 0, stream>>>(pooledP, pooledL, cov_acc);
    kernelC<<<1, 128, 0, stream>>>(cov_acc, bce_sum, valid, out);
}

// Round 3
// 233.934 us; speedup vs baseline: 2.0551x; 1.2412x over previous
//
#include <hip/hip_runtime.h>
#include <math.h>
#include <stdint.h>

#define NUM_CL 21
#define NB 4
#define H 512
#define W 512
#define PH 171
#define PW 171
#define NHH 169
#define NWW 169
#define M_TOT (NHH*NWW)          // 28561
#define NCP (NB*NUM_CL)          // 84
#define PPLANE (PH*PW)           // 29241
#define ACC_PER 189
#define SLICES 8
#define MCHUNK ((M_TOT + SLICES - 1)/SLICES)   // 3571
#define POS_ALPHA 5e-4
#define NBLKA (NB*NUM_CL*PH)     // 14364

__device__ __forceinline__ int upIdx(int lo, int hi) {
    return lo*9 - (lo*(lo-1))/2 + (hi - lo);
}
__device__ __forceinline__ int tri(int d, int e) { return d*(d+1)/2 + e; }

// ---------------- Kernel A: fused sigmoid + BCE + 3x3/3 max-pool ----------------
// One block per (n, c, pooled-row ph): 14364 blocks x 128 threads, one barrier.
// Thread q covers cols 4q..4q+3 across the 3 source rows.
__global__ __launch_bounds__(128) void kernelA(
    const float* __restrict__ logits, const int* __restrict__ labels,
    float* __restrict__ pooledP, unsigned char* __restrict__ pooledL,
    float* __restrict__ bce_part, unsigned int* __restrict__ cnt_part)
{
    int blk = blockIdx.x;
    int c  = blk % NUM_CL;
    int t2 = blk / NUM_CL;
    int ph = t2 % PH;
    int n  = t2 / PH;
    int q  = threadIdx.x;            // 0..127
    int col0 = q << 2;

    __shared__ float         svP[W];
    __shared__ unsigned char svL[W];
    __shared__ float         rbce[2];
    __shared__ unsigned int  rcnt[2];

    const float* lgp = logits + (size_t)(n*NUM_CL + c) * (H*W);
    const int*   lbp = labels + (size_t)n * (H*W);

    float vP[4] = {-INFINITY, -INFINITY, -INFINITY, -INFINITY};
    int   vL[4] = {0,0,0,0};
    float bce = 0.f;
    unsigned int cnt = 0;

    int rbase = 3*ph - 1;
    #pragma unroll
    for (int rr = 0; rr < 3; ++rr) {
        int r = rbase + rr;
        if (r < 0 || r >= H) continue;       // uniform across block
        float4 x4 = *(const float4*)(lgp + (size_t)r*W + col0);
        int4   l4 = *(const int4*)  (lbp + (size_t)r*W + col0);
        float xs[4] = {x4.x, x4.y, x4.z, x4.w};
        int   ls[4] = {l4.x, l4.y, l4.z, l4.w};
        #pragma unroll
        for (int k = 0; k < 4; ++k) {
            int lab = ls[k];
            float x = xs[k];
            float m = (lab < NUM_CL) ? 1.f : 0.f;
            float y = (lab == c) ? 1.f : 0.f;
            float te = __expf(-fabsf(x));
            float u  = 1.f + te;
            float sp = __logf(u);                    // log1p(te)
            float rc = __builtin_amdgcn_rcpf(u);     // 1/(1+te)
            bce += m * (fmaxf(x, 0.f) - x*y + sp);
            float sig = (x >= 0.f) ? rc : te*rc;
            float p = sig*m + 1e-6f;
            vP[k] = fmaxf(vP[k], p);
            vL[k] |= (lab == c);
            cnt += (unsigned)(lab < NUM_CL);
        }
    }

    ((float4*)svP)[q] = make_float4(vP[0], vP[1], vP[2], vP[3]);
    uchar4 u4;
    u4.x = (unsigned char)vL[0]; u4.y = (unsigned char)vL[1];
    u4.z = (unsigned char)vL[2]; u4.w = (unsigned char)vL[3];
    ((uchar4*)svL)[q] = u4;

    // wave-level BCE/count reduction (2 waves)
    #pragma unroll
    for (int o = 32; o > 0; o >>= 1) {
        bce += __shfl_down(bce, o, 64);
        cnt += __shfl_down(cnt, o, 64);
    }
    int lane = threadIdx.x & 63, wv = threadIdx.x >> 6;
    if (lane == 0) { rbce[wv] = bce; rcnt[wv] = cnt; }
    __syncthreads();

    // horizontal pool from LDS (stride-3 reads: 2-way bank alias = free)
    for (int pw = threadIdx.x; pw < PW; pw += 128) {
        int c0 = 3*pw - 1; if (c0 < 0) c0 = 0;
        int c1 = 3*pw + 2; if (c1 > W) c1 = W;
        float pm = -INFINITY; int lm = 0;
        for (int qq = c0; qq < c1; ++qq) {
            pm = fmaxf(pm, svP[qq]);
            lm |= svL[qq];
        }
        size_t o = ((size_t)(n*NUM_CL + c) * PH + ph) * PW + pw;
        pooledP[o] = pm;
        pooledL[o] = (unsigned char)lm;
    }

    if (threadIdx.x == 0) {
        bce_part[blk] = rbce[0] + rbce[1];
        if (c == 0) cnt_part[t2] = rcnt[0] + rcnt[1];
    }
}

// ---------------- Kernel B: raw-moment accumulation, 2 register groups ----------------
__global__ __launch_bounds__(256) void kernelB(
    const float* __restrict__ pooledP, const unsigned char* __restrict__ pooledL,
    double* __restrict__ cov_acc)
{
    int nc    = blockIdx.x;
    int slice = blockIdx.y;
    int grp   = blockIdx.z;
    const float* P = pooledP + (size_t)nc * PPLANE;
    const unsigned char* L = pooledL + (size_t)nc * PPLANE;

    int mlo = slice * MCHUNK;
    int mhi = mlo + MCHUNK; if (mhi > M_TOT) mhi = M_TOT;

    __shared__ float red[4][108];
    int lane = threadIdx.x & 63;
    int wave = threadIdx.x >> 6;

    auto wred = [&](float v) -> float {
        #pragma unroll
        for (int o = 32; o > 0; o >>= 1) v += __shfl_down(v, o, 64);
        return v;
    };

    double* acc = cov_acc + (size_t)nc * ACC_PER;

    if (grp == 0) {
        float sl[9], sp[9], cll[45], cpp[45];
        #pragma unroll
        for (int d = 0; d < 9; ++d) { sl[d] = 0.f; sp[d] = 0.f; }
        #pragma unroll
        for (int k = 0; k < 45; ++k) { cll[k] = 0.f; cpp[k] = 0.f; }

        for (int m = mlo + (int)threadIdx.x; m < mhi; m += 256) {
            int i = m / NWW;
            int j = m - i * NWW;
            int base = i * PW + j;
            float la[9], pr[9];
            #pragma unroll
            for (int dy = 0; dy < 3; ++dy)
                #pragma unroll
                for (int dx = 0; dx < 3; ++dx) {
                    int o = base + dy*PW + dx;
                    pr[dy*3+dx] = P[o];
                    la[dy*3+dx] = (float)L[o];
                }
            #pragma unroll
            for (int d = 0; d < 9; ++d) { sl[d] += la[d]; sp[d] += pr[d]; }
            int k = 0;
            #pragma unroll
            for (int d = 0; d < 9; ++d)
                #pragma unroll
                for (int e = d; e < 9; ++e) {
                    cll[k] += la[d]*la[e];
                    cpp[k] += pr[d]*pr[e];
                    ++k;
                }
        }

        #pragma unroll
        for (int d = 0; d < 9; ++d) { float r = wred(sl[d]);  if (lane == 0) red[wave][d]     = r; }
        #pragma unroll
        for (int d = 0; d < 9; ++d) { float r = wred(sp[d]);  if (lane == 0) red[wave][9+d]   = r; }
        #pragma unroll
        for (int k = 0; k < 45; ++k) { float r = wred(cll[k]); if (lane == 0) red[wave][18+k] = r; }
        #pragma unroll
        for (int k = 0; k < 45; ++k) { float r = wred(cpp[k]); if (lane == 0) red[wave][63+k] = r; }
        __syncthreads();
        for (int v = threadIdx.x; v < 108; v += 256) {
            float s = red[0][v] + red[1][v] + red[2][v] + red[3][v];
            atomicAdd(&acc[v], (double)s);
        }
    } else {
        float clp[81];
        #pragma unroll
        for (int k = 0; k < 81; ++k) clp[k] = 0.f;

        for (int m = mlo + (int)threadIdx.x; m < mhi; m += 256) {
            int i = m / NWW;
            int j = m - i * NWW;
            int base = i * PW + j;
            float la[9], pr[9];
            #pragma unroll
            for (int dy = 0; dy < 3; ++dy)
                #pragma unroll
                for (int dx = 0; dx < 3; ++dx) {
                    int o = base + dy*PW + dx;
                    pr[dy*3+dx] = P[o];
                    la[dy*3+dx] = (float)L[o];
                }
            #pragma unroll
            for (int d = 0; d < 9; ++d)
                #pragma unroll
                for (int e = 0; e < 9; ++e) clp[d*9+e] += la[d]*pr[e];
        }

        #pragma unroll
        for (int k = 0; k < 81; ++k) { float r = wred(clp[k]); if (lane == 0) red[wave][k] = r; }
        __syncthreads();
        for (int v = threadIdx.x; v < 81; v += 256) {
            float s = red[0][v] + red[1][v] + red[2][v] + red[3][v];
            atomicAdd(&acc[108 + v], (double)s);
        }
    }
}

// ---------------- Kernel C: BCE reduce + per-(n,c) 9x9 solve + combine ----------------
__global__ __launch_bounds__(128) void kernelC(
    const double* __restrict__ cov_acc,
    const float* __restrict__ bce_part,
    const unsigned int* __restrict__ cnt_part,
    float* __restrict__ out)
{
    int t = threadIdx.x;

    __shared__ double sb[128];
    __shared__ unsigned long long sc[128];
    double bs = 0.0;
    for (int i = t; i < NBLKA; i += 128) bs += (double)bce_part[i];
    unsigned long long cs = 0;
    for (int i = t; i < NB*PH; i += 128) cs += cnt_part[i];
    sb[t] = bs; sc[t] = cs;
    __syncthreads();
    #pragma unroll
    for (int s = 64; s > 0; s >>= 1) {
        if (t < s) { sb[t] += sb[t + s]; sc[t] += sc[t + s]; }
        __syncthreads();
    }

    float contrib = 0.f;
    if (t < NCP) {
        const double* acc = cov_acc + (size_t)t * ACC_PER;
        const double Minv = 1.0 / (double)M_TOT;
        double Sl[9], Sp[9];
        #pragma unroll
        for (int d = 0; d < 9; ++d) { Sl[d] = acc[d]; Sp[d] = acc[9+d]; }

        float A[45];  // pr_cov + alpha*I (lower tri)
        float G[45];  // la_cov, later appro_var
        float B[81];  // la_pr_cov rows, later W rows
        #pragma unroll
        for (int d = 0; d < 9; ++d) {
            #pragma unroll
            for (int e = 0; e <= d; ++e) {
                int ku = upIdx(e, d);
                double vp = acc[63+ku] - Sp[d]*Sp[e]*Minv;
                double vl = acc[18+ku] - Sl[d]*Sl[e]*Minv;
                if (d == e) vp += POS_ALPHA;
                A[tri(d,e)] = (float)vp;
                G[tri(d,e)] = (float)vl;
            }
        }
        #pragma unroll
        for (int d = 0; d < 9; ++d) {
            #pragma unroll
            for (int e = 0; e < 9; ++e)
                B[d*9+e] = (float)(acc[108 + d*9 + e] - Sl[d]*Sp[e]*Minv);
        }

        // Cholesky of A (lower, in place)
        #pragma unroll
        for (int d = 0; d < 9; ++d) {
            float s = A[tri(d,d)];
            #pragma unroll
            for (int f = 0; f < d; ++f) { float v = A[tri(d,f)]; s -= v*v; }
            float ldd = sqrtf(s);
            A[tri(d,d)] = ldd;
            float inv = 1.f / ldd;
            #pragma unroll
            for (int e = d+1; e < 9; ++e) {
                float s2 = A[tri(e,d)];
                #pragma unroll
                for (int f = 0; f < d; ++f) s2 -= A[tri(e,f)] * A[tri(d,f)];
                A[tri(e,d)] = s2 * inv;
            }
        }

        // forward substitution: row d of B <- solve L w = LP[d,:]^T
        #pragma unroll
        for (int d = 0; d < 9; ++d) {
            #pragma unroll
            for (int e = 0; e < 9; ++e) {
                float s = B[d*9+e];
                #pragma unroll
                for (int f = 0; f < e; ++f) s -= A[tri(e,f)] * B[d*9+f];
                B[d*9+e] = s / A[tri(e,e)];
            }
        }

        // appro_var = la_cov - W W^T + alpha*I
        #pragma unroll
        for (int d = 0; d < 9; ++d) {
            #pragma unroll
            for (int g = 0; g <= d; ++g) {
                float qv = 0.f;
                #pragma unroll
                for (int e = 0; e < 9; ++e) qv += B[d*9+e] * B[g*9+e];
                float v = G[tri(d,g)] - qv;
                if (d == g) v += (float)POS_ALPHA;
                G[tri(d,g)] = v;
            }
        }

        // Cholesky of G, sum log(diag + 1e-8)
        float sumlog = 0.f;
        #pragma unroll
        for (int d = 0; d < 9; ++d) {
            float s = G[tri(d,d)];
            #pragma unroll
            for (int f = 0; f < d; ++f) { float v = G[tri(d,f)]; s -= v*v; }
            float ldd = sqrtf(s);
            G[tri(d,d)] = ldd;
            sumlog += logf(ldd + 1e-8f);
            float inv = 1.f / ldd;
            #pragma unroll
            for (int e = d+1; e < 9; ++e) {
                float s2 = G[tri(e,d)];
                #pragma unroll
                for (int f = 0; f < d; ++f) s2 -= G[tri(e,f)] * G[tri(d,f)];
                G[tri(e,d)] = s2 * inv;
            }
        }
        contrib = sumlog * (1.0f / 36.0f);   // /(N * HALF_D) = /(4*9)
    }

    __shared__ float sred[128];
    sred[t] = contrib;
    __syncthreads();
    #pragma unroll
    for (int s = 64; s > 0; s >>= 1) {
        if (t < s) sred[t] += sred[t + s];
        __syncthreads();
    }
    if (t == 0) {
        double bce_loss = sb[0] / ((double)sc[0] + 1.0);
        out[0] = (float)(0.5 * bce_loss + 0.5 * (double)sred[0]);
    }
}

extern "C" void kernel_launch(void* const* d_in, const int* in_sizes, int n_in,
                              void* d_out, int out_size, void* d_ws, size_t ws_size,
                              hipStream_t stream)
{
    (void)in_sizes; (void)n_in; (void)out_size; (void)ws_size;
    const float* logits = (const float*)d_in[0];
    const int*   labels = (const int*)d_in[1];
    float* out = (float*)d_out;

    uint8_t* w = (uint8_t*)d_ws;
    double* cov_acc = (double*)w;                                  // 84*189*8 = 127008 B
    size_t off = (size_t)NCP * ACC_PER * 8;
    float* bce_part = (float*)(w + off);       off += (size_t)NBLKA * 4;       // 57456 B
    unsigned int* cnt_part = (unsigned int*)(w + off); off += (size_t)(NB*PH) * 4; // 2736 B
    float* pooledP = (float*)(w + off);        off += (size_t)NCP * PPLANE * 4;    // 9.8 MB
    unsigned char* pooledL = (unsigned char*)(w + off);                            // 2.5 MB

    hipMemsetAsync(cov_acc, 0, (size_t)NCP * ACC_PER * 8, stream);

    kernelA<<<NBLKA, 128, 0, stream>>>(logits, labels, pooledP, pooledL, bce_part, cnt_part);
    kernelB<<<dim3(NCP, SLICES, 2), 256, 0, stream>>>(pooledP, pooledL, cov_acc);
    kernelC<<<1, 128, 0, stream>>>(cov_acc, bce_part, cnt_part, out);
}